// Round 3
// baseline (1843.315 us; speedup 1.0000x reference)
//
#include <hip/hip_runtime.h>

typedef unsigned short ushort_t;
typedef unsigned int uint_t;

typedef __attribute__((ext_vector_type(8))) __bf16 bf16x8_t;
typedef __attribute__((ext_vector_type(8))) short s16x8;
typedef __attribute__((ext_vector_type(4))) float f32x4;

#define T_TOK 2048
#define H_DIM 2048
#define I_DIM 1024
#define N_EXP 64
#define TOPK 8
#define MT_MAX 6     // covers up to 768 tokens/expert (mean 256, sigma ~16)
#define LSTR 136     // LDS row stride in bf16 elems (BK=128 + 8 pad)

// Raw barrier: does NOT drain vmcnt -> in-flight global loads stay outstanding.
#define BAR_RAW()  asm volatile("s_barrier" ::: "memory")
// LDS-visibility barrier: drain ds ops (lgkm) then barrier; vmcnt untouched.
#define BAR_LGKM() asm volatile("s_waitcnt lgkmcnt(0)\n\ts_barrier" ::: "memory")

__device__ inline f32x4 mfma_bf16(s16x8 a, s16x8 b, f32x4 c) {
  return __builtin_amdgcn_mfma_f32_16x16x32_bf16(
      __builtin_bit_cast(bf16x8_t, a), __builtin_bit_cast(bf16x8_t, b), c, 0, 0, 0);
}

__device__ inline ushort_t f2bf(float f) {
  uint_t u = __float_as_uint(f);
  u += 0x7FFFu + ((u >> 16) & 1u);   // round-to-nearest-even
  return (ushort_t)(u >> 16);
}

// packed f32x2 -> bf16x2 (RNE), 1 instruction
__device__ inline uint_t pkbf(float a, float b) {
  uint_t r;
  asm("v_cvt_pk_bf16_f32 %0, %1, %2" : "=v"(r) : "v"(a), "v"(b));
  return r;
}
// two float4 -> uint4 (8 bf16)
__device__ inline uint4 pk8(float4 u, float4 v) {
  uint4 w;
  w.x = pkbf(u.x, u.y); w.y = pkbf(u.z, u.w);
  w.z = pkbf(v.x, v.y); w.w = pkbf(v.z, v.w);
  return w;
}

// ---------------- Router: logits[t][e] = sum_h x[t][h] * gw[e][h] (fp32 exact) ----------
__global__ __launch_bounds__(256) void router_kernel(const float* __restrict__ X,
                                                     const float* __restrict__ GW,
                                                     float* __restrict__ logits) {
  __shared__ float xs[4][H_DIM];
  int tid = threadIdx.x;
  int t0 = blockIdx.x * 4;
  const float4* src = (const float4*)(X + (size_t)t0 * H_DIM);
  float4* dst = (float4*)(&xs[0][0]);
#pragma unroll
  for (int j = 0; j < 8; ++j) dst[tid + 256 * j] = src[tid + 256 * j];
  __syncthreads();
  int wave = tid >> 6, lane = tid & 63;
  int t = t0 + wave;
  const float4* w = (const float4*)(GW + (size_t)lane * H_DIM);
  const float4* xr = (const float4*)(&xs[wave][0]);
  float acc = 0.f;
  for (int i = 0; i < H_DIM / 4; ++i) {
    float4 a = xr[i];
    float4 b = w[i];
    acc = fmaf(a.x, b.x, acc);
    acc = fmaf(a.y, b.y, acc);
    acc = fmaf(a.z, b.z, acc);
    acc = fmaf(a.w, b.w, acc);
  }
  logits[(size_t)t * N_EXP + lane] = acc;
}

// ---------------- Softmax + top-8 per token (one wave per token) -----------------------
__global__ __launch_bounds__(256) void topk_kernel(const float* __restrict__ logits,
                                                   int* __restrict__ counts,
                                                   int* __restrict__ sel_e,
                                                   float* __restrict__ sel_w) {
  int tid = threadIdx.x;
  int wave = tid >> 6, lane = tid & 63;
  int t = blockIdx.x * 4 + wave;
  float l = logits[(size_t)t * N_EXP + lane];
  float m = l;
#pragma unroll
  for (int s = 32; s; s >>= 1) m = fmaxf(m, __shfl_xor(m, s, 64));
  float p = __expf(l - m);
  float sum = p;
#pragma unroll
  for (int s = 32; s; s >>= 1) sum += __shfl_xor(sum, s, 64);
  float prob = p / sum;

  float val = l;
#pragma unroll
  for (int k = 0; k < TOPK; ++k) {
    float bv = val;
    int bi = lane;
#pragma unroll
    for (int s = 32; s; s >>= 1) {
      float ov = __shfl_xor(bv, s, 64);
      int oi = __shfl_xor(bi, s, 64);
      if (ov > bv || (ov == bv && oi < bi)) { bv = ov; bi = oi; }
    }
    float bw = __shfl(prob, bi, 64);
    if (lane == 0) {
      sel_e[t * TOPK + k] = bi;
      sel_w[t * TOPK + k] = bw;
      atomicAdd(&counts[bi], 1);
    }
    if (lane == bi) val = -INFINITY;
  }
}

// ---------------- Prefix sum over 64 expert counts -------------------------------------
__global__ void scan_kernel(const int* __restrict__ counts, int* __restrict__ offsets,
                            int* __restrict__ cursor) {
  if (threadIdx.x == 0) {
    int acc = 0;
    for (int e = 0; e < N_EXP; ++e) { offsets[e] = acc; acc += counts[e]; }
    offsets[N_EXP] = acc;
  }
  if (threadIdx.x < N_EXP) cursor[threadIdx.x] = 0;
}

// ---------------- Assign packed rows ---------------------------------------------------
__global__ __launch_bounds__(256) void assign_kernel(const int* __restrict__ sel_e,
                                                     const float* __restrict__ sel_w,
                                                     const int* __restrict__ offsets,
                                                     int* __restrict__ cursor,
                                                     int* __restrict__ token_of,
                                                     float* __restrict__ weight_of) {
  int idx = blockIdx.x * 256 + threadIdx.x;  // 0..16383
  int t = idx >> 3;
  int e = sel_e[idx];
  float w = sel_w[idx];
  int r = offsets[e] + atomicAdd(&cursor[e], 1);
  token_of[r] = t;
  weight_of[r] = w;
}

// ---------------- Fused gate+up GEMM + SiLU -> act (bf16), BK=128 pipelined ------------
// grid: 64 experts x MT_MAX m-tiles x 8 n-tiles; tile 128x128 (x2 proj), K-step 128
__global__ __launch_bounds__(256, 1) void gateup_kernel(const float* __restrict__ X,
                                                        const float* __restrict__ Wg,
                                                        const float* __restrict__ Wu,
                                                        const int* __restrict__ offsets,
                                                        const int* __restrict__ token_of,
                                                        ushort_t* __restrict__ act) {
  int bid = blockIdx.x;
  int e = bid / (MT_MAX * 8);
  int mt = (bid % (MT_MAX * 8)) / 8;
  int nt = bid % 8;
  int base = offsets[e];
  int Me = offsets[e + 1] - base;
  if (mt * 128 >= Me) return;

  __shared__ ushort_t As[128 * LSTR];   // 34816 B
  __shared__ ushort_t Bgs[128 * LSTR];
  __shared__ ushort_t Bus[128 * LSTR];  // total 104448 B
  __shared__ int stok[128];

  int tid = threadIdx.x;
  if (tid < 128) {
    int gm = mt * 128 + tid;
    int cm = gm < Me ? gm : (Me - 1);
    stok[tid] = token_of[base + cm];
  }
  __syncthreads();

  int srow = tid >> 1;        // 0..127
  int sh = (tid & 1) * 64;    // float col offset within BK=128
  int wave = tid >> 6, lane = tid & 63;
  int wm = wave >> 1, wn = wave & 1;

  const float* pA = X + (size_t)stok[srow] * H_DIM + sh;
  const float* pG = Wg + ((size_t)e * I_DIM + nt * 128 + srow) * H_DIM + sh;
  const float* pU = Wu + ((size_t)e * I_DIM + nt * 128 + srow) * H_DIM + sh;

  f32x4 accg[4][4], accu[4][4];
#pragma unroll
  for (int i = 0; i < 4; ++i)
#pragma unroll
    for (int j = 0; j < 4; ++j) { accg[i][j] = (f32x4)0.f; accu[i][j] = (f32x4)0.f; }

  float4 rA[16], rG[16], rU[16];
#pragma unroll
  for (int j = 0; j < 16; ++j) {
    rA[j] = *(const float4*)(pA + 4 * j);
    rG[j] = *(const float4*)(pG + 4 * j);
    rU[j] = *(const float4*)(pU + 4 * j);
  }

  for (int k0 = 0; k0 < H_DIM; k0 += 128) {
    BAR_RAW();  // prev iter's ds_reads already in regs; prefetch loads cross freely
#pragma unroll
    for (int j = 0; j < 8; ++j) {
      *(uint4*)&As[srow * LSTR + sh + 8 * j] = pk8(rA[2 * j], rA[2 * j + 1]);
      *(uint4*)&Bgs[srow * LSTR + sh + 8 * j] = pk8(rG[2 * j], rG[2 * j + 1]);
      *(uint4*)&Bus[srow * LSTR + sh + 8 * j] = pk8(rU[2 * j], rU[2 * j + 1]);
    }
    if (k0 + 128 < H_DIM) {
      int kn = k0 + 128;
#pragma unroll
      for (int j = 0; j < 16; ++j) {
        rA[j] = *(const float4*)(pA + kn + 4 * j);
        rG[j] = *(const float4*)(pG + kn + 4 * j);
        rU[j] = *(const float4*)(pU + kn + 4 * j);
      }
    }
    BAR_LGKM();  // ds_writes visible; vmcnt untouched (prefetch in flight)

#pragma unroll
    for (int ks = 0; ks < 4; ++ks) {
      int kc = ks * 32 + (lane >> 4) * 8;
      s16x8 af[4], bg[4], bu[4];
#pragma unroll
      for (int mf = 0; mf < 4; ++mf)
        af[mf] = *(const s16x8*)&As[(wm * 64 + mf * 16 + (lane & 15)) * LSTR + kc];
#pragma unroll
      for (int nf = 0; nf < 4; ++nf) {
        bg[nf] = *(const s16x8*)&Bgs[(wn * 64 + nf * 16 + (lane & 15)) * LSTR + kc];
        bu[nf] = *(const s16x8*)&Bus[(wn * 64 + nf * 16 + (lane & 15)) * LSTR + kc];
      }
#pragma unroll
      for (int mf = 0; mf < 4; ++mf)
#pragma unroll
        for (int nf = 0; nf < 4; ++nf) {
          accg[mf][nf] = mfma_bf16(af[mf], bg[nf], accg[mf][nf]);
          accu[mf][nf] = mfma_bf16(af[mf], bu[nf], accu[mf][nf]);
        }
    }
  }

  // epilogue: act = silu(g)*u -> bf16
#pragma unroll
  for (int mf = 0; mf < 4; ++mf)
#pragma unroll
    for (int nf = 0; nf < 4; ++nf) {
      f32x4 g = accg[mf][nf], u = accu[mf][nf];
#pragma unroll
      for (int r = 0; r < 4; ++r) {
        int mloc = wm * 64 + mf * 16 + (lane >> 4) * 4 + r;
        int gm = mt * 128 + mloc;
        if (gm < Me) {
          float gv = g[r], uv = u[r];
          float s = gv / (1.f + __expf(-gv));
          int col = nt * 128 + wn * 64 + nf * 16 + (lane & 15);
          act[(size_t)(base + gm) * I_DIM + col] = f2bf(s * uv);
        }
      }
    }
}

// ---------------- Down GEMM + weighted scatter to out, BK=128 pipelined ----------------
// grid: 64 experts x MT_MAX m-tiles x 16 n-tiles; tile 128x128, K-step 128
__global__ __launch_bounds__(256) void down_kernel(const ushort_t* __restrict__ act,
                                                   const float* __restrict__ Wd,
                                                   const int* __restrict__ offsets,
                                                   const int* __restrict__ token_of,
                                                   const float* __restrict__ weight_of,
                                                   float* __restrict__ out) {
  int bid = blockIdx.x;
  int e = bid / (MT_MAX * 16);
  int mt = (bid % (MT_MAX * 16)) / 16;
  int nt = bid % 16;
  int base = offsets[e];
  int Me = offsets[e + 1] - base;
  if (mt * 128 >= Me) return;

  __shared__ ushort_t As[128 * LSTR];
  __shared__ ushort_t Bs[128 * LSTR];  // total 69632 B
  __shared__ int stok[128];
  __shared__ float sw[128];

  int tid = threadIdx.x;
  if (tid < 128) {
    int gm = mt * 128 + tid;
    int ok = gm < Me;
    int cm = ok ? gm : (Me - 1);
    stok[tid] = token_of[base + cm];
    sw[tid] = ok ? weight_of[base + gm] : 0.f;
  }
  __syncthreads();

  int srow = tid >> 1;
  int sh = (tid & 1) * 64;    // elem col offset within BK=128
  int wave = tid >> 6, lane = tid & 63;
  int wm = wave >> 1, wn = wave & 1;

  int rclamp = mt * 128 + srow;
  if (rclamp >= Me) rclamp = Me - 1;
  const ushort_t* pA = act + (size_t)(base + rclamp) * I_DIM + sh;
  const float* pB = Wd + ((size_t)e * H_DIM + nt * 128 + srow) * I_DIM + sh;

  f32x4 acc[4][4];
#pragma unroll
  for (int i = 0; i < 4; ++i)
#pragma unroll
    for (int j = 0; j < 4; ++j) acc[i][j] = (f32x4)0.f;

  s16x8 rA[8];
  float4 rB[16];
#pragma unroll
  for (int j = 0; j < 8; ++j) rA[j] = *(const s16x8*)(pA + 8 * j);
#pragma unroll
  for (int j = 0; j < 16; ++j) rB[j] = *(const float4*)(pB + 4 * j);

  for (int k0 = 0; k0 < I_DIM; k0 += 128) {
    BAR_RAW();
#pragma unroll
    for (int j = 0; j < 8; ++j)
      *(s16x8*)&As[srow * LSTR + sh + 8 * j] = rA[j];
#pragma unroll
    for (int j = 0; j < 8; ++j)
      *(uint4*)&Bs[srow * LSTR + sh + 8 * j] = pk8(rB[2 * j], rB[2 * j + 1]);
    if (k0 + 128 < I_DIM) {
      int kn = k0 + 128;
#pragma unroll
      for (int j = 0; j < 8; ++j) rA[j] = *(const s16x8*)(pA + kn + 8 * j);
#pragma unroll
      for (int j = 0; j < 16; ++j) rB[j] = *(const float4*)(pB + kn + 4 * j);
    }
    BAR_LGKM();

#pragma unroll
    for (int ks = 0; ks < 4; ++ks) {
      int kc = ks * 32 + (lane >> 4) * 8;
      s16x8 af[4], bf[4];
#pragma unroll
      for (int mf = 0; mf < 4; ++mf)
        af[mf] = *(const s16x8*)&As[(wm * 64 + mf * 16 + (lane & 15)) * LSTR + kc];
#pragma unroll
      for (int nf = 0; nf < 4; ++nf)
        bf[nf] = *(const s16x8*)&Bs[(wn * 64 + nf * 16 + (lane & 15)) * LSTR + kc];
#pragma unroll
      for (int mf = 0; mf < 4; ++mf)
#pragma unroll
        for (int nf = 0; nf < 4; ++nf)
          acc[mf][nf] = mfma_bf16(af[mf], bf[nf], acc[mf][nf]);
    }
  }

#pragma unroll
  for (int mf = 0; mf < 4; ++mf)
#pragma unroll
    for (int nf = 0; nf < 4; ++nf) {
      f32x4 v = acc[mf][nf];
#pragma unroll
      for (int r = 0; r < 4; ++r) {
        int mloc = wm * 64 + mf * 16 + (lane >> 4) * 4 + r;
        int gm = mt * 128 + mloc;
        if (gm < Me) {
          int t = stok[mloc];
          float w = sw[mloc];
          int h = nt * 128 + wn * 64 + nf * 16 + (lane & 15);
          unsafeAtomicAdd(&out[(size_t)t * H_DIM + h], w * v[r]);
        }
      }
    }
}

// ---------------------------------------------------------------------------------------
extern "C" void kernel_launch(void* const* d_in, const int* in_sizes, int n_in,
                              void* d_out, int out_size, void* d_ws, size_t ws_size,
                              hipStream_t stream) {
  const float* X = (const float*)d_in[0];
  const float* GW = (const float*)d_in[1];
  const float* Wg = (const float*)d_in[2];
  const float* Wu = (const float*)d_in[3];
  const float* Wd = (const float*)d_in[4];
  float* out = (float*)d_out;
  float* logits = out + (size_t)T_TOK * H_DIM;

  char* ws = (char*)d_ws;
  int* counts = (int*)ws;                       // 256 B
  int* cursor = (int*)(ws + 256);               // 256 B
  int* offsets = (int*)(ws + 512);              // 260 B
  int* sel_e = (int*)(ws + 1024);               // 64 KB
  float* sel_w = (float*)(ws + 1024 + 65536);   // 64 KB
  int* token_of = (int*)(ws + 1024 + 2 * 65536);
  float* weight_of = (float*)(ws + 1024 + 3 * 65536);
  ushort_t* act = (ushort_t*)(ws + 524288);     // 16384*1024*2 = 32 MB

  hipMemsetAsync(out, 0, (size_t)T_TOK * H_DIM * sizeof(float), stream);
  hipMemsetAsync(ws, 0, 1024, stream);

  router_kernel<<<T_TOK / 4, 256, 0, stream>>>(X, GW, logits);
  topk_kernel<<<T_TOK / 4, 256, 0, stream>>>(logits, counts, sel_e, sel_w);
  scan_kernel<<<1, 64, 0, stream>>>(counts, offsets, cursor);
  assign_kernel<<<(T_TOK * TOPK) / 256, 256, 0, stream>>>(sel_e, sel_w, offsets, cursor,
                                                          token_of, weight_of);
  gateup_kernel<<<N_EXP * MT_MAX * 8, 256, 0, stream>>>(X, Wg, Wu, offsets, token_of, act);
  down_kernel<<<N_EXP * MT_MAX * 16, 256, 0, stream>>>(act, Wd, offsets, token_of,
                                                       weight_of, out);
}

// Round 4
// 999.510 us; speedup vs baseline: 1.8442x; 1.8442x over previous
//
#include <hip/hip_runtime.h>

typedef unsigned short ushort_t;
typedef unsigned int uint_t;

typedef __attribute__((ext_vector_type(8))) __bf16 bf16x8_t;
typedef __attribute__((ext_vector_type(8))) short s16x8;
typedef __attribute__((ext_vector_type(4))) float f32x4;

#define T_TOK 2048
#define H_DIM 2048
#define I_DIM 1024
#define N_EXP 64
#define TOPK 8
#define MT_MAX 6     // covers up to 768 tokens/expert (mean 256)
#define LSTR 40      // LDS row stride in bf16 elems (BK=32 + 8 pad)

// Raw barrier: does NOT drain vmcnt -> in-flight global loads stay outstanding.
#define BAR_RAW()  asm volatile("s_barrier" ::: "memory")
// LDS-visibility barrier: drain ds ops (lgkm) then barrier; vmcnt untouched.
#define BAR_LGKM() asm volatile("s_waitcnt lgkmcnt(0)\n\ts_barrier" ::: "memory")

__device__ inline f32x4 mfma_bf16(s16x8 a, s16x8 b, f32x4 c) {
  return __builtin_amdgcn_mfma_f32_16x16x32_bf16(
      __builtin_bit_cast(bf16x8_t, a), __builtin_bit_cast(bf16x8_t, b), c, 0, 0, 0);
}

__device__ inline ushort_t f2bf(float f) {
  uint_t u = __float_as_uint(f);
  u += 0x7FFFu + ((u >> 16) & 1u);   // round-to-nearest-even
  return (ushort_t)(u >> 16);
}

// packed f32x2 -> bf16x2 (RNE), 1 instruction
__device__ inline uint_t pkbf(float a, float b) {
  uint_t r;
  asm("v_cvt_pk_bf16_f32 %0, %1, %2" : "=v"(r) : "v"(a), "v"(b));
  return r;
}
// float4 -> 4 bf16 (8 B)
__device__ inline uint2 pk4(float4 v) {
  uint2 w;
  w.x = pkbf(v.x, v.y);
  w.y = pkbf(v.z, v.w);
  return w;
}

// ---------------- Router: logits[t][e] = sum_h x[t][h] * gw[e][h] (fp32 exact) ----------
__global__ __launch_bounds__(256) void router_kernel(const float* __restrict__ X,
                                                     const float* __restrict__ GW,
                                                     float* __restrict__ logits) {
  __shared__ float xs[4][H_DIM];
  int tid = threadIdx.x;
  int t0 = blockIdx.x * 4;
  const float4* src = (const float4*)(X + (size_t)t0 * H_DIM);
  float4* dst = (float4*)(&xs[0][0]);
#pragma unroll
  for (int j = 0; j < 8; ++j) dst[tid + 256 * j] = src[tid + 256 * j];
  __syncthreads();
  int wave = tid >> 6, lane = tid & 63;
  int t = t0 + wave;
  const float4* w = (const float4*)(GW + (size_t)lane * H_DIM);
  const float4* xr = (const float4*)(&xs[wave][0]);
  float acc = 0.f;
  for (int i = 0; i < H_DIM / 4; ++i) {
    float4 a = xr[i];
    float4 b = w[i];
    acc = fmaf(a.x, b.x, acc);
    acc = fmaf(a.y, b.y, acc);
    acc = fmaf(a.z, b.z, acc);
    acc = fmaf(a.w, b.w, acc);
  }
  logits[(size_t)t * N_EXP + lane] = acc;
}

// ---------------- Softmax + top-8 per token (one wave per token) -----------------------
__global__ __launch_bounds__(256) void topk_kernel(const float* __restrict__ logits,
                                                   int* __restrict__ counts,
                                                   int* __restrict__ sel_e,
                                                   float* __restrict__ sel_w) {
  int tid = threadIdx.x;
  int wave = tid >> 6, lane = tid & 63;
  int t = blockIdx.x * 4 + wave;
  float l = logits[(size_t)t * N_EXP + lane];
  float m = l;
#pragma unroll
  for (int s = 32; s; s >>= 1) m = fmaxf(m, __shfl_xor(m, s, 64));
  float p = __expf(l - m);
  float sum = p;
#pragma unroll
  for (int s = 32; s; s >>= 1) sum += __shfl_xor(sum, s, 64);
  float prob = p / sum;

  float val = l;
#pragma unroll
  for (int k = 0; k < TOPK; ++k) {
    float bv = val;
    int bi = lane;
#pragma unroll
    for (int s = 32; s; s >>= 1) {
      float ov = __shfl_xor(bv, s, 64);
      int oi = __shfl_xor(bi, s, 64);
      if (ov > bv || (ov == bv && oi < bi)) { bv = ov; bi = oi; }
    }
    float bw = __shfl(prob, bi, 64);
    if (lane == 0) {
      sel_e[t * TOPK + k] = bi;
      sel_w[t * TOPK + k] = bw;
      atomicAdd(&counts[bi], 1);
    }
    if (lane == bi) val = -INFINITY;
  }
}

// ---------------- Prefix sum over 64 expert counts -------------------------------------
__global__ void scan_kernel(const int* __restrict__ counts, int* __restrict__ offsets,
                            int* __restrict__ cursor) {
  if (threadIdx.x == 0) {
    int acc = 0;
    for (int e = 0; e < N_EXP; ++e) { offsets[e] = acc; acc += counts[e]; }
    offsets[N_EXP] = acc;
  }
  if (threadIdx.x < N_EXP) cursor[threadIdx.x] = 0;
}

// ---------------- Assign packed rows ---------------------------------------------------
__global__ __launch_bounds__(256) void assign_kernel(const int* __restrict__ sel_e,
                                                     const float* __restrict__ sel_w,
                                                     const int* __restrict__ offsets,
                                                     int* __restrict__ cursor,
                                                     int* __restrict__ token_of,
                                                     float* __restrict__ weight_of) {
  int idx = blockIdx.x * 256 + threadIdx.x;  // 0..16383
  int t = idx >> 3;
  int e = sel_e[idx];
  float w = sel_w[idx];
  int r = offsets[e] + atomicAdd(&cursor[e], 1);
  token_of[r] = t;
  weight_of[r] = w;
}

// ---------------- Fused gate+up GEMM + SiLU -> act (bf16), coalesced staging -----------
// grid: 64 experts x MT_MAX m-tiles x 8 n-tiles; tile 128x128 (x2 proj), K-step 32
// Staging map: lane-contiguous — thread loads row (32j + tid>>3), float cols
// (tid&7)*4 .. +3; a wave instruction = 8 rows x 128 B contiguous runs.
__global__ __launch_bounds__(256) void gateup_kernel(const float* __restrict__ X,
                                                     const float* __restrict__ Wg,
                                                     const float* __restrict__ Wu,
                                                     const int* __restrict__ offsets,
                                                     const int* __restrict__ token_of,
                                                     ushort_t* __restrict__ act) {
  int bid = blockIdx.x;
  int e = bid / (MT_MAX * 8);
  int mt = (bid % (MT_MAX * 8)) / 8;
  int nt = bid % 8;
  int base = offsets[e];
  int Me = offsets[e + 1] - base;
  if (mt * 128 >= Me) return;

  __shared__ ushort_t As[128 * LSTR];
  __shared__ ushort_t Bgs[128 * LSTR];
  __shared__ ushort_t Bus[128 * LSTR];
  __shared__ int stok[128];

  int tid = threadIdx.x;
  if (tid < 128) {
    int gm = mt * 128 + tid;
    int cm = gm < Me ? gm : (Me - 1);
    stok[tid] = token_of[base + cm];
  }
  __syncthreads();

  int lr = tid >> 3;          // 0..31: row within 32-row group
  int lc = (tid & 7) * 4;     // float col 0,4,...,28
  int wave = tid >> 6, lane = tid & 63;
  int wm = wave >> 1, wn = wave & 1;

  // per-j row pointers (rows 32j + lr)
  const float* pA[4];
  const float* pG[4];
  const float* pU[4];
#pragma unroll
  for (int j = 0; j < 4; ++j) {
    int r = 32 * j + lr;
    pA[j] = X + (size_t)stok[r] * H_DIM + lc;
    pG[j] = Wg + ((size_t)e * I_DIM + nt * 128 + r) * H_DIM + lc;
    pU[j] = Wu + ((size_t)e * I_DIM + nt * 128 + r) * H_DIM + lc;
  }

  f32x4 accg[4][4], accu[4][4];
#pragma unroll
  for (int i = 0; i < 4; ++i)
#pragma unroll
    for (int j = 0; j < 4; ++j) { accg[i][j] = (f32x4)0.f; accu[i][j] = (f32x4)0.f; }

  float4 ra[4], rg[4], ru[4];
#pragma unroll
  for (int j = 0; j < 4; ++j) {
    ra[j] = *(const float4*)(pA[j]);
    rg[j] = *(const float4*)(pG[j]);
    ru[j] = *(const float4*)(pU[j]);
  }

  for (int k0 = 0; k0 < H_DIM; k0 += 32) {
    BAR_RAW();  // prev iter's ds_reads already consumed; prefetch crosses freely
#pragma unroll
    for (int j = 0; j < 4; ++j) {
      int r = 32 * j + lr;
      *(uint2*)&As[r * LSTR + lc] = pk4(ra[j]);
      *(uint2*)&Bgs[r * LSTR + lc] = pk4(rg[j]);
      *(uint2*)&Bus[r * LSTR + lc] = pk4(ru[j]);
    }
    if (k0 + 32 < H_DIM) {
      int kn = k0 + 32;
#pragma unroll
      for (int j = 0; j < 4; ++j) {
        ra[j] = *(const float4*)(pA[j] + kn);
        rg[j] = *(const float4*)(pG[j] + kn);
        ru[j] = *(const float4*)(pU[j] + kn);
      }
    }
    BAR_LGKM();  // ds_writes visible; vmcnt untouched (prefetch in flight)

    s16x8 af[4], bg[4], bu[4];
#pragma unroll
    for (int mf = 0; mf < 4; ++mf)
      af[mf] = *(const s16x8*)&As[(wm * 64 + mf * 16 + (lane & 15)) * LSTR + (lane >> 4) * 8];
#pragma unroll
    for (int nf = 0; nf < 4; ++nf) {
      bg[nf] = *(const s16x8*)&Bgs[(wn * 64 + nf * 16 + (lane & 15)) * LSTR + (lane >> 4) * 8];
      bu[nf] = *(const s16x8*)&Bus[(wn * 64 + nf * 16 + (lane & 15)) * LSTR + (lane >> 4) * 8];
    }
#pragma unroll
    for (int mf = 0; mf < 4; ++mf)
#pragma unroll
      for (int nf = 0; nf < 4; ++nf) {
        accg[mf][nf] = mfma_bf16(af[mf], bg[nf], accg[mf][nf]);
        accu[mf][nf] = mfma_bf16(af[mf], bu[nf], accu[mf][nf]);
      }
  }

  // epilogue: act = silu(g)*u -> bf16
#pragma unroll
  for (int mf = 0; mf < 4; ++mf)
#pragma unroll
    for (int nf = 0; nf < 4; ++nf) {
      f32x4 g = accg[mf][nf], u = accu[mf][nf];
#pragma unroll
      for (int r = 0; r < 4; ++r) {
        int mloc = wm * 64 + mf * 16 + (lane >> 4) * 4 + r;
        int gm = mt * 128 + mloc;
        if (gm < Me) {
          float gv = g[r], uv = u[r];
          float s = gv / (1.f + __expf(-gv));
          int col = nt * 128 + wn * 64 + nf * 16 + (lane & 15);
          act[(size_t)(base + gm) * I_DIM + col] = f2bf(s * uv);
        }
      }
    }
}

// ---------------- Down GEMM + weighted scatter to out, coalesced staging ---------------
// grid: 64 experts x MT_MAX m-tiles x 16 n-tiles; tile 128x128, K-step 32
__global__ __launch_bounds__(256) void down_kernel(const ushort_t* __restrict__ act,
                                                   const float* __restrict__ Wd,
                                                   const int* __restrict__ offsets,
                                                   const int* __restrict__ token_of,
                                                   const float* __restrict__ weight_of,
                                                   float* __restrict__ out) {
  int bid = blockIdx.x;
  int e = bid / (MT_MAX * 16);
  int mt = (bid % (MT_MAX * 16)) / 16;
  int nt = bid % 16;
  int base = offsets[e];
  int Me = offsets[e + 1] - base;
  if (mt * 128 >= Me) return;

  __shared__ ushort_t As[128 * LSTR];
  __shared__ ushort_t Bs[128 * LSTR];
  __shared__ int stok[128];
  __shared__ float sw[128];

  int tid = threadIdx.x;
  if (tid < 128) {
    int gm = mt * 128 + tid;
    int ok = gm < Me;
    int cm = ok ? gm : (Me - 1);
    stok[tid] = token_of[base + cm];
    sw[tid] = ok ? weight_of[base + gm] : 0.f;
  }
  __syncthreads();

  int wave = tid >> 6, lane = tid & 63;
  int wm = wave >> 1, wn = wave & 1;

  // A (act, bf16, 64 B per row per k-step): row 64j + tid>>2, col (tid&3)*8 elems
  int ar = tid >> 2;          // 0..63
  int ac = (tid & 3) * 8;     // bf16 col 0,8,16,24
  const ushort_t* pA[2];
#pragma unroll
  for (int j = 0; j < 2; ++j) {
    int r = mt * 128 + 64 * j + ar;
    if (r >= Me) r = Me - 1;
    pA[j] = act + (size_t)(base + r) * I_DIM + ac;
  }
  // B (Wd, fp32, 128 B per row per k-step): row 32j + tid>>3, col (tid&7)*4 floats
  int br = tid >> 3;          // 0..31
  int bc = (tid & 7) * 4;
  const float* pB[4];
#pragma unroll
  for (int j = 0; j < 4; ++j)
    pB[j] = Wd + ((size_t)e * H_DIM + nt * 128 + 32 * j + br) * I_DIM + bc;

  f32x4 acc[4][4];
#pragma unroll
  for (int i = 0; i < 4; ++i)
#pragma unroll
    for (int j = 0; j < 4; ++j) acc[i][j] = (f32x4)0.f;

  s16x8 rA[2];
  float4 rB[4];
#pragma unroll
  for (int j = 0; j < 2; ++j) rA[j] = *(const s16x8*)(pA[j]);
#pragma unroll
  for (int j = 0; j < 4; ++j) rB[j] = *(const float4*)(pB[j]);

  for (int k0 = 0; k0 < I_DIM; k0 += 32) {
    BAR_RAW();
#pragma unroll
    for (int j = 0; j < 2; ++j)
      *(s16x8*)&As[(64 * j + ar) * LSTR + ac] = rA[j];
#pragma unroll
    for (int j = 0; j < 4; ++j)
      *(uint2*)&Bs[(32 * j + br) * LSTR + bc] = pk4(rB[j]);
    if (k0 + 32 < I_DIM) {
      int kn = k0 + 32;
#pragma unroll
      for (int j = 0; j < 2; ++j) rA[j] = *(const s16x8*)(pA[j] + kn);
#pragma unroll
      for (int j = 0; j < 4; ++j) rB[j] = *(const float4*)(pB[j] + kn);
    }
    BAR_LGKM();

    s16x8 af[4], bf[4];
#pragma unroll
    for (int mf = 0; mf < 4; ++mf)
      af[mf] = *(const s16x8*)&As[(wm * 64 + mf * 16 + (lane & 15)) * LSTR + (lane >> 4) * 8];
#pragma unroll
    for (int nf = 0; nf < 4; ++nf)
      bf[nf] = *(const s16x8*)&Bs[(wn * 64 + nf * 16 + (lane & 15)) * LSTR + (lane >> 4) * 8];
#pragma unroll
    for (int mf = 0; mf < 4; ++mf)
#pragma unroll
      for (int nf = 0; nf < 4; ++nf)
        acc[mf][nf] = mfma_bf16(af[mf], bf[nf], acc[mf][nf]);
  }

#pragma unroll
  for (int mf = 0; mf < 4; ++mf)
#pragma unroll
    for (int nf = 0; nf < 4; ++nf) {
      f32x4 v = acc[mf][nf];
#pragma unroll
      for (int r = 0; r < 4; ++r) {
        int mloc = wm * 64 + mf * 16 + (lane >> 4) * 4 + r;
        int gm = mt * 128 + mloc;
        if (gm < Me) {
          int t = stok[mloc];
          float w = sw[mloc];
          int h = nt * 128 + wn * 64 + nf * 16 + (lane & 15);
          unsafeAtomicAdd(&out[(size_t)t * H_DIM + h], w * v[r]);
        }
      }
    }
}

// ---------------------------------------------------------------------------------------
extern "C" void kernel_launch(void* const* d_in, const int* in_sizes, int n_in,
                              void* d_out, int out_size, void* d_ws, size_t ws_size,
                              hipStream_t stream) {
  const float* X = (const float*)d_in[0];
  const float* GW = (const float*)d_in[1];
  const float* Wg = (const float*)d_in[2];
  const float* Wu = (const float*)d_in[3];
  const float* Wd = (const float*)d_in[4];
  float* out = (float*)d_out;
  float* logits = out + (size_t)T_TOK * H_DIM;

  char* ws = (char*)d_ws;
  int* counts = (int*)ws;                       // 256 B
  int* cursor = (int*)(ws + 256);               // 256 B
  int* offsets = (int*)(ws + 512);              // 260 B
  int* sel_e = (int*)(ws + 1024);               // 64 KB
  float* sel_w = (float*)(ws + 1024 + 65536);   // 64 KB
  int* token_of = (int*)(ws + 1024 + 2 * 65536);
  float* weight_of = (float*)(ws + 1024 + 3 * 65536);
  ushort_t* act = (ushort_t*)(ws + 524288);     // 16384*1024*2 = 32 MB

  hipMemsetAsync(out, 0, (size_t)T_TOK * H_DIM * sizeof(float), stream);
  hipMemsetAsync(ws, 0, 1024, stream);

  router_kernel<<<T_TOK / 4, 256, 0, stream>>>(X, GW, logits);
  topk_kernel<<<T_TOK / 4, 256, 0, stream>>>(logits, counts, sel_e, sel_w);
  scan_kernel<<<1, 64, 0, stream>>>(counts, offsets, cursor);
  assign_kernel<<<(T_TOK * TOPK) / 256, 256, 0, stream>>>(sel_e, sel_w, offsets, cursor,
                                                          token_of, weight_of);
  gateup_kernel<<<N_EXP * MT_MAX * 8, 256, 0, stream>>>(X, Wg, Wu, offsets, token_of, act);
  down_kernel<<<N_EXP * MT_MAX * 16, 256, 0, stream>>>(act, Wd, offsets, token_of,
                                                       weight_of, out);
}